// Round 4
// baseline (843.517 us; speedup 1.0000x reference)
//
#include <hip/hip_runtime.h>
#include <hip/hip_bf16.h>

#define BATCH 256
#define TSTEPS 1024
#define NIN 128
#define NL 64
#define NH 128
#define NOUT 32

typedef __attribute__((ext_vector_type(8))) short short8;
typedef __attribute__((ext_vector_type(4))) float f32x4;
typedef __attribute__((ext_vector_type(2))) unsigned int u32x2;

__device__ inline int pk2(float x, float y) {
    __hip_bfloat162 h = __float22bfloat162_rn(make_float2(x, y));
    union { __hip_bfloat162 h; int i; } u;
    u.h = h;
    return u.i;
}
__device__ inline short bf1(float x) {
    __hip_bfloat16 h = __float2bfloat16(x);
    union { __hip_bfloat16 h; short s; } u;
    u.h = h;
    return u.s;
}

// lgkmcnt drain + barrier; vmcnt (u-prefetch) stays in flight across it
#define WG_BARRIER() asm volatile("s_waitcnt lgkmcnt(0)\n\ts_barrier" ::: "memory")

// ---------------------------------------------------------------------------
// In-register D->B fragment redistribution for 16x16x32 bf16 MFMA.
// permlane32_swap + permlane16_swap, 2x per pk-component = 4 VALU ops.
// a0,a1 = P0,P1 of even 16-row tile; b0,b1 = P0,P1 of odd tile.
// ---------------------------------------------------------------------------
__device__ inline short8 mk_bfrag(int a0, int a1, int b0, int b1) {
    u32x2 s0 = __builtin_amdgcn_permlane32_swap((unsigned)a0, (unsigned)b0, false, false);
    u32x2 t0 = __builtin_amdgcn_permlane16_swap(s0[0], s0[1], false, false);
    u32x2 s1 = __builtin_amdgcn_permlane32_swap((unsigned)a1, (unsigned)b1, false, false);
    u32x2 t1 = __builtin_amdgcn_permlane16_swap(s1[0], s1[1], false, false);
    union { int i[4]; short8 s; } u;
    u.i[0] = (int)t0[0];
    u.i[1] = (int)t1[0];
    u.i[2] = (int)t0[1];
    u.i[3] = (int)t1[1];
    return u.s;
}

// ---------------------------------------------------------------------------
// Pass 1: u'[t][b][l] = bf16( C[l,:]·s[b,t,:] + h1[l] )   (unchanged)
// ---------------------------------------------------------------------------
__launch_bounds__(256, 1)
__global__ void ugemm_mfma(const float* __restrict__ input,
                           const float* __restrict__ C,
                           const float* __restrict__ h1,
                           unsigned short* __restrict__ u16) {
    const int lane = threadIdx.x & 63;
    const int wv   = threadIdx.x >> 6;
    const int c = lane & 15;
    const int q = lane >> 4;
    const long wbase = ((long)blockIdx.x * 4 + wv) * 128;  // first row (b*1024+t)

    short8 cA[4][4];
    #pragma unroll
    for (int mt = 0; mt < 4; ++mt)
        #pragma unroll
        for (int kf = 0; kf < 4; ++kf) {
            const float* p = C + (mt * 16 + c) * NIN + kf * 32 + q * 8;
            float4 r0 = *(const float4*)p;
            float4 r1 = *(const float4*)(p + 4);
            union { short8 s; int i[4]; } f;
            f.i[0] = pk2(r0.x, r0.y); f.i[1] = pk2(r0.z, r0.w);
            f.i[2] = pk2(r1.x, r1.y); f.i[3] = pk2(r1.z, r1.w);
            cA[mt][kf] = f.s;
        }
    f32x4 h1f[4];
    #pragma unroll
    for (int mt = 0; mt < 4; ++mt)
        h1f[mt] = *(const f32x4*)(h1 + mt * 16 + q * 4);

    float4 raw[8], rawn[8];
    {
        const float* sr = input + (wbase + c) * NIN;
        #pragma unroll
        for (int kf = 0; kf < 4; ++kf) {
            raw[2*kf]   = *(const float4*)(sr + kf * 32 + q * 8);
            raw[2*kf+1] = *(const float4*)(sr + kf * 32 + q * 8 + 4);
        }
    }

    for (int it = 0; it < 8; ++it) {
        if (it < 7) {
            const float* sr = input + (wbase + (it + 1) * 16 + c) * NIN;
            #pragma unroll
            for (int kf = 0; kf < 4; ++kf) {
                rawn[2*kf]   = *(const float4*)(sr + kf * 32 + q * 8);
                rawn[2*kf+1] = *(const float4*)(sr + kf * 32 + q * 8 + 4);
            }
        }
        short8 bf[4];
        #pragma unroll
        for (int kf = 0; kf < 4; ++kf) {
            union { short8 s; int i[4]; } f;
            f.i[0] = pk2(raw[2*kf].x,   raw[2*kf].y);
            f.i[1] = pk2(raw[2*kf].z,   raw[2*kf].w);
            f.i[2] = pk2(raw[2*kf+1].x, raw[2*kf+1].y);
            f.i[3] = pk2(raw[2*kf+1].z, raw[2*kf+1].w);
            bf[kf] = f.s;
        }
        long rr = wbase + it * 16 + c;
        int b = (int)(rr >> 10), t = (int)(rr & 1023);
        unsigned short* ubase = u16 + ((size_t)t * 256 + b) * 64 + q * 4;
        #pragma unroll
        for (int mt = 0; mt < 4; ++mt) {
            f32x4 acc = __builtin_amdgcn_mfma_f32_16x16x32_bf16(cA[mt][0], bf[0], h1f[mt], 0, 0, 0);
            acc = __builtin_amdgcn_mfma_f32_16x16x32_bf16(cA[mt][1], bf[1], acc, 0, 0, 0);
            acc = __builtin_amdgcn_mfma_f32_16x16x32_bf16(cA[mt][2], bf[2], acc, 0, 0, 0);
            acc = __builtin_amdgcn_mfma_f32_16x16x32_bf16(cA[mt][3], bf[3], acc, 0, 0, 0);
            *(int2*)(ubase + mt * 16) =
                make_int2(pk2(acc[0], acc[1]), pk2(acc[2], acc[3]));
        }
        #pragma unroll
        for (int j = 0; j < 8; ++j) raw[j] = rawn[j];
    }
}

// ---------------------------------------------------------------------------
// Pass 2: 4-wave, ONE barrier per step.
//  wave w: GEMM1 H-tiles {2w,2w+1} from full bz (4 MFMA depth-2) ->
//  relu/pack/permlane (intra-wave!) -> own K-frag w of H ->
//  GEMM2: partials of ALL 4 z-tiles over frag w (4 MFMA depth-1; C-in:
//  wave w carries cin=A*z+u for tile w, zero otherwise) ->
//  publish f32 partials (4x b128), ONE barrier, read 3 partners (12x b128),
//  redundant reduce -> full z' on every wave -> permlane -> next bz frags.
// Grid 16 x 256 (4 waves, one per SIMD).
// ---------------------------------------------------------------------------
__launch_bounds__(256, 1)
__global__ void plrnn_scan_ks(const float* __restrict__ A,
                              const float* __restrict__ W1,
                              const float* __restrict__ W2,
                              const float* __restrict__ h2,
                              const unsigned short* __restrict__ u16,
                              const float* __restrict__ Wout,
                              const float* __restrict__ bout,
                              float* __restrict__ out) {
    // pbuf[buf][wave][lt][lane] : f32x4 partial, lane-contiguous b128
    __shared__ __attribute__((aligned(16))) float pbuf[2][4][4][64][4];

    const int lane = threadIdx.x & 63;
    const int w    = threadIdx.x >> 6;     // wave 0..3
    const int c = lane & 15;               // batch column
    const int q = lane >> 4;               // quad
    const int bbase = blockIdx.x * 16;

    // ---- static weight fragments ----
    // W2: own 2 H-tiles (2w, 2w+1), K=64 (2 frags each)
    short8 aw2[2][2];
    #pragma unroll
    for (int i = 0; i < 2; ++i)
        #pragma unroll
        for (int kt = 0; kt < 2; ++kt) {
            const float* p = W2 + ((2 * w + i) * 16 + c) * NL + kt * 32 + q * 8;
            short8 f;
            #pragma unroll
            for (int j = 0; j < 8; ++j) f[j] = bf1(p[j]);
            aw2[i][kt] = f;
        }
    // W1: all 4 z-tiles, own K-frag w (columns [32w, 32w+32))
    short8 aw1[4];
    #pragma unroll
    for (int lt = 0; lt < 4; ++lt) {
        const float* p = W1 + (lt * 16 + c) * NH + w * 32 + q * 8;
        short8 f;
        #pragma unroll
        for (int j = 0; j < 8; ++j) f[j] = bf1(p[j]);
        aw1[lt] = f;
    }
    f32x4 h2f[2];
    #pragma unroll
    for (int i = 0; i < 2; ++i)
        h2f[i] = *(const f32x4*)(h2 + (2 * w + i) * 16 + q * 4);
    // A slice for own z-tile w
    const f32x4 af = *(const f32x4*)(A + w * 16 + q * 4);

    // u' stream for own tile w: (t*256 + b)*64 + w*16 + q*4 ; stride/t = 16384
    const unsigned short* ub = u16 + (size_t)(bbase + c) * 64 + w * 16 + q * 4;
    int2 uP = *(const int2*)ub;                // u(0)
    int2 uQ = *(const int2*)(ub + 16384);      // u(1)

    // z0 = 0 -> bz frags zero; cin(0) = u(0) for own tile
    short8 bz0 = (short8){0, 0, 0, 0, 0, 0, 0, 0};
    short8 bz1 = (short8){0, 0, 0, 0, 0, 0, 0, 0};
    f32x4 cin;
    cin[0] = __int_as_float(uP.x << 16);
    cin[1] = __int_as_float(uP.x & 0xffff0000);
    cin[2] = __int_as_float(uP.y << 16);
    cin[3] = __int_as_float(uP.y & 0xffff0000);
    const f32x4 zero4 = {0.f, 0.f, 0.f, 0.f};

    auto step = [&](int2& pf, const int2& tail, const int T, const int buf) {
        // ---- GEMM1: own 2 H-tiles (2 chains, depth 2) ----
        f32x4 ha[2];
        #pragma unroll
        for (int i = 0; i < 2; ++i)
            ha[i] = __builtin_amdgcn_mfma_f32_16x16x32_bf16(aw2[i][0], bz0, h2f[i], 0, 0, 0);
        #pragma unroll
        for (int i = 0; i < 2; ++i)
            ha[i] = __builtin_amdgcn_mfma_f32_16x16x32_bf16(aw2[i][1], bz1, ha[i], 0, 0, 0);

        // relu + pack + intra-wave permlane -> own H K-frag (rows [32w,32w+32))
        int hp[2][2];
        #pragma unroll
        for (int i = 0; i < 2; ++i) {
            hp[i][0] = pk2(fmaxf(ha[i][0], 0.f), fmaxf(ha[i][1], 0.f));
            hp[i][1] = pk2(fmaxf(ha[i][2], 0.f), fmaxf(ha[i][3], 0.f));
        }
        short8 bh = mk_bfrag(hp[0][0], hp[0][1], hp[1][0], hp[1][1]);

        // ---- GEMM2: partials of all 4 z-tiles over frag w (depth 1) ----
        // C-in: cin enters exactly once (on wave w for tile w)
        f32x4 za[4];
        #pragma unroll
        for (int lt = 0; lt < 4; ++lt)
            za[lt] = __builtin_amdgcn_mfma_f32_16x16x32_bf16(
                aw1[lt], bh, (lt == w) ? cin : zero4, 0, 0, 0);

        // ---- publish partials ----
        #pragma unroll
        for (int lt = 0; lt < 4; ++lt)
            *(f32x4*)&pbuf[buf][w][lt][lane][0] = za[lt];

        WG_BARRIER();

        // prefetch u(T+2) for own tile; stays in flight across MFMAs
        const int tp = (T + 2 < TSTEPS) ? T + 2 : TSTEPS - 1;
        pf = *(const int2*)(ub + (size_t)tp * 16384);

        // ---- read 3 partners' partials and reduce (redundant on all waves) ----
        #pragma unroll
        for (int d = 1; d < 4; ++d) {
            const int v = (w + d) & 3;
            #pragma unroll
            for (int lt = 0; lt < 4; ++lt) {
                f32x4 p = *(const f32x4*)&pbuf[buf][v][lt][lane][0];
                za[lt][0] += p[0]; za[lt][1] += p[1];
                za[lt][2] += p[2]; za[lt][3] += p[3];
            }
        }

        // clip -> full z' (replicated), pack, permlane -> next bz frags
        int zp[4][2];
        f32x4 zw;   // own tile's z' (for next cin)
        #pragma unroll
        for (int lt = 0; lt < 4; ++lt) {
            f32x4 zc;
            zc[0] = __builtin_amdgcn_fmed3f(za[lt][0], -5.f, 5.f);
            zc[1] = __builtin_amdgcn_fmed3f(za[lt][1], -5.f, 5.f);
            zc[2] = __builtin_amdgcn_fmed3f(za[lt][2], -5.f, 5.f);
            zc[3] = __builtin_amdgcn_fmed3f(za[lt][3], -5.f, 5.f);
            zp[lt][0] = pk2(zc[0], zc[1]);
            zp[lt][1] = pk2(zc[2], zc[3]);
            if (lt == w) zw = zc;
        }
        bz0 = mk_bfrag(zp[0][0], zp[0][1], zp[1][0], zp[1][1]);
        bz1 = mk_bfrag(zp[2][0], zp[2][1], zp[3][0], zp[3][1]);

        // next cin = A*z'(own tile) + u(T+1)
        cin[0] = fmaf(zw[0], af[0], __int_as_float(tail.x << 16));
        cin[1] = fmaf(zw[1], af[1], __int_as_float(tail.x & 0xffff0000));
        cin[2] = fmaf(zw[2], af[2], __int_as_float(tail.y << 16));
        cin[3] = fmaf(zw[3], af[3], __int_as_float(tail.y & 0xffff0000));
    };

    for (int t = 0; t < TSTEPS; t += 2) {
        step(uP, uQ, t, 0);       // even: prefetch->uP, tail uses uQ = u(t+1)
        step(uQ, uP, t + 1, 1);   // odd:  prefetch->uQ, tail uses uP = u(t+2)
    }

    // ---- epilogue: out = Wout @ z_T + bout (waves 0,1; bz frags replicated) ----
    if (w < 2) {
        short8 wo[2];
        #pragma unroll
        for (int kt = 0; kt < 2; ++kt) {
            const float* p = Wout + (w * 16 + c) * NL + kt * 32 + q * 8;
            short8 f;
            #pragma unroll
            for (int j = 0; j < 8; ++j) f[j] = bf1(p[j]);
            wo[kt] = f;
        }
        f32x4 ob = *(const f32x4*)(bout + w * 16 + q * 4);
        f32x4 acc = __builtin_amdgcn_mfma_f32_16x16x32_bf16(wo[0], bz0, ob, 0, 0, 0);
        acc = __builtin_amdgcn_mfma_f32_16x16x32_bf16(wo[1], bz1, acc, 0, 0, 0);
        *(f32x4*)&out[(size_t)(bbase + c) * 32 + w * 16 + q * 4] = acc;
    }
}

extern "C" void kernel_launch(void* const* d_in, const int* in_sizes, int n_in,
                              void* d_out, int out_size, void* d_ws, size_t ws_size,
                              hipStream_t stream) {
    const float* input = (const float*)d_in[0];
    const float* A     = (const float*)d_in[1];
    const float* W1    = (const float*)d_in[2];
    const float* W2    = (const float*)d_in[3];
    const float* h1    = (const float*)d_in[4];
    const float* h2    = (const float*)d_in[5];
    const float* C     = (const float*)d_in[6];
    const float* Wout  = (const float*)d_in[7];
    const float* bout  = (const float*)d_in[8];
    float* out = (float*)d_out;

    unsigned short* u16 = (unsigned short*)d_ws;   // 256*1024*64 bf16 = 33.5 MB

    ugemm_mfma<<<dim3(512), dim3(256), 0, stream>>>(input, C, h1, u16);
    plrnn_scan_ks<<<dim3(16), dim3(256), 0, stream>>>(
        A, W1, W2, h2, u16, Wout, bout, out);
}

// Round 5
// 450.581 us; speedup vs baseline: 1.8721x; 1.8721x over previous
//
#include <hip/hip_runtime.h>
#include <hip/hip_bf16.h>

#define BATCH 256
#define TSTEPS 1024
#define NIN 128
#define NL 64
#define NH 128
#define NOUT 32

typedef __attribute__((ext_vector_type(8))) short short8;
typedef __attribute__((ext_vector_type(4))) float f32x4;

__device__ inline int pk2(float x, float y) {
    __hip_bfloat162 h = __float22bfloat162_rn(make_float2(x, y));
    union { __hip_bfloat162 h; int i; } u;
    u.h = h;
    return u.i;
}
__device__ inline short bf1(float x) {
    __hip_bfloat16 h = __float2bfloat16(x);
    union { __hip_bfloat16 h; short s; } u;
    u.h = h;
    return u.s;
}

// lgkmcnt drain + barrier; vmcnt (u-prefetch) stays in flight across it
#define WG_BARRIER() asm volatile("s_waitcnt lgkmcnt(0)\n\ts_barrier" ::: "memory")

// ---------------------------------------------------------------------------
// Pass 1: u'[t][b][l] = bf16( C[l,:]·s[b,t,:] + h1[l] )   (unchanged)
// ---------------------------------------------------------------------------
__launch_bounds__(256, 1)
__global__ void ugemm_mfma(const float* __restrict__ input,
                           const float* __restrict__ C,
                           const float* __restrict__ h1,
                           unsigned short* __restrict__ u16) {
    const int lane = threadIdx.x & 63;
    const int wv   = threadIdx.x >> 6;
    const int c = lane & 15;
    const int q = lane >> 4;
    const long wbase = ((long)blockIdx.x * 4 + wv) * 128;  // first row (b*1024+t)

    short8 cA[4][4];
    #pragma unroll
    for (int mt = 0; mt < 4; ++mt)
        #pragma unroll
        for (int kf = 0; kf < 4; ++kf) {
            const float* p = C + (mt * 16 + c) * NIN + kf * 32 + q * 8;
            float4 r0 = *(const float4*)p;
            float4 r1 = *(const float4*)(p + 4);
            union { short8 s; int i[4]; } f;
            f.i[0] = pk2(r0.x, r0.y); f.i[1] = pk2(r0.z, r0.w);
            f.i[2] = pk2(r1.x, r1.y); f.i[3] = pk2(r1.z, r1.w);
            cA[mt][kf] = f.s;
        }
    f32x4 h1f[4];
    #pragma unroll
    for (int mt = 0; mt < 4; ++mt)
        h1f[mt] = *(const f32x4*)(h1 + mt * 16 + q * 4);

    float4 raw[8], rawn[8];
    {
        const float* sr = input + (wbase + c) * NIN;
        #pragma unroll
        for (int kf = 0; kf < 4; ++kf) {
            raw[2*kf]   = *(const float4*)(sr + kf * 32 + q * 8);
            raw[2*kf+1] = *(const float4*)(sr + kf * 32 + q * 8 + 4);
        }
    }

    for (int it = 0; it < 8; ++it) {
        if (it < 7) {
            const float* sr = input + (wbase + (it + 1) * 16 + c) * NIN;
            #pragma unroll
            for (int kf = 0; kf < 4; ++kf) {
                rawn[2*kf]   = *(const float4*)(sr + kf * 32 + q * 8);
                rawn[2*kf+1] = *(const float4*)(sr + kf * 32 + q * 8 + 4);
            }
        }
        short8 bf[4];
        #pragma unroll
        for (int kf = 0; kf < 4; ++kf) {
            union { short8 s; int i[4]; } f;
            f.i[0] = pk2(raw[2*kf].x,   raw[2*kf].y);
            f.i[1] = pk2(raw[2*kf].z,   raw[2*kf].w);
            f.i[2] = pk2(raw[2*kf+1].x, raw[2*kf+1].y);
            f.i[3] = pk2(raw[2*kf+1].z, raw[2*kf+1].w);
            bf[kf] = f.s;
        }
        long rr = wbase + it * 16 + c;
        int b = (int)(rr >> 10), t = (int)(rr & 1023);
        unsigned short* ubase = u16 + ((size_t)t * 256 + b) * 64 + q * 4;
        #pragma unroll
        for (int mt = 0; mt < 4; ++mt) {
            f32x4 acc = __builtin_amdgcn_mfma_f32_16x16x32_bf16(cA[mt][0], bf[0], h1f[mt], 0, 0, 0);
            acc = __builtin_amdgcn_mfma_f32_16x16x32_bf16(cA[mt][1], bf[1], acc, 0, 0, 0);
            acc = __builtin_amdgcn_mfma_f32_16x16x32_bf16(cA[mt][2], bf[2], acc, 0, 0, 0);
            acc = __builtin_amdgcn_mfma_f32_16x16x32_bf16(cA[mt][3], bf[3], acc, 0, 0, 0);
            *(int2*)(ubase + mt * 16) =
                make_int2(pk2(acc[0], acc[1]), pk2(acc[2], acc[3]));
        }
        #pragma unroll
        for (int j = 0; j < 8; ++j) raw[j] = rawn[j];
    }
}

// ---------------------------------------------------------------------------
// Pass 2: champion structure (4-wave M-split, 2 barriers/step) + polish:
//  - zero-copy pf/tail u-prefetch rotation (cin computed at step end)
//  - fmed3 clip
//  - MFMA2 as two depth-2 accumulator chains + add (latency hedge)
// Grid 16 WGs x 256 thr; WG = 16 batches. Wave w: H tiles {2w,2w+1},
// z tile w.
// ---------------------------------------------------------------------------
__launch_bounds__(256, 1)
__global__ void plrnn_scan_mfma(const float* __restrict__ A,
                                const float* __restrict__ W1,
                                const float* __restrict__ W2,
                                const float* __restrict__ h2,
                                const unsigned short* __restrict__ u16,
                                const float* __restrict__ Wout,
                                const float* __restrict__ bout,
                                float* __restrict__ out) {
    __shared__ __attribute__((aligned(16))) unsigned short zbuf[16 * 72];
    __shared__ __attribute__((aligned(16))) unsigned short hbuf[16 * 136];

    const int lane = threadIdx.x & 63;
    const int w    = threadIdx.x >> 6;     // wave 0..3
    const int c = lane & 15;               // batch col
    const int q = lane >> 4;               // quad
    const int bbase = blockIdx.x * 16;

    // ---- static weight fragments ----
    short8 aw2[2][2];   // H tiles mt = 2w, 2w+1 ; K = 64 (2 frags)
    #pragma unroll
    for (int i = 0; i < 2; ++i)
        #pragma unroll
        for (int kt = 0; kt < 2; ++kt) {
            const float* p = W2 + ((2*w + i) * 16 + c) * NL + kt * 32 + q * 8;
            short8 f;
            #pragma unroll
            for (int j = 0; j < 8; ++j) f[j] = bf1(p[j]);
            aw2[i][kt] = f;
        }
    short8 aw1[4];      // Z tile lt = w ; K = 128 (4 frags)
    #pragma unroll
    for (int kt = 0; kt < 4; ++kt) {
        const float* p = W1 + (w * 16 + c) * NH + kt * 32 + q * 8;
        short8 f;
        #pragma unroll
        for (int j = 0; j < 8; ++j) f[j] = bf1(p[j]);
        aw1[kt] = f;
    }
    f32x4 h2f[2];
    #pragma unroll
    for (int i = 0; i < 2; ++i)
        h2f[i] = *(const f32x4*)(h2 + (2*w + i) * 16 + q * 4);
    const f32x4 af = *(const f32x4*)(A + w * 16 + q * 4);
    const f32x4 zero4 = {0.f, 0.f, 0.f, 0.f};

    // u' stream: index (t*256 + bbase+c)*64 + w*16 + q*4 ; stride/t = 16384
    const unsigned short* ub = u16 + ((size_t)(bbase + c)) * 64 + w * 16 + q * 4;
    int2 uP = *(const int2*)ub;                // u(0)
    int2 uQ = *(const int2*)(ub + 16384);      // u(1)

    f32x4 zf = {0.f, 0.f, 0.f, 0.f};

    // cin(t=0) = u(0)   (A*z0 = 0)
    f32x4 cin;
    cin[0] = __int_as_float(uP.x << 16);
    cin[1] = __int_as_float(uP.x & 0xffff0000);
    cin[2] = __int_as_float(uP.y << 16);
    cin[3] = __int_as_float(uP.y & 0xffff0000);

    // one timestep; pf <- prefetch target (u(T+2)), tail <- u(T+1) for next cin
    auto step = [&](int2& pf, const int2& tail, const int T) {
        // ---- publish z (wave w owns latents [16w,16w+16)) ----
        *(int2*)&zbuf[c * 72 + w * 16 + q * 4] =
            make_int2(pk2(zf[0], zf[1]), pk2(zf[2], zf[3]));
        WG_BARRIER();
        short8 bz0 = *(short8*)&zbuf[c * 72 + q * 8];
        short8 bz1 = *(short8*)&zbuf[c * 72 + 32 + q * 8];

        // prefetch u'(T+2) — stays in flight across both MFMA phases
        const int tp = (T + 2 < TSTEPS) ? T + 2 : TSTEPS - 1;
        pf = *(const int2*)(ub + (size_t)tp * 16384);

        // ---- MFMA1: H rows [32w,32w+32) = relu(W2 @ Z + h2) ----
        #pragma unroll
        for (int i = 0; i < 2; ++i) {
            f32x4 acc = __builtin_amdgcn_mfma_f32_16x16x32_bf16(aw2[i][0], bz0, h2f[i], 0, 0, 0);
            acc = __builtin_amdgcn_mfma_f32_16x16x32_bf16(aw2[i][1], bz1, acc, 0, 0, 0);
            *(int2*)&hbuf[c * 136 + (2*w + i) * 16 + q * 4] =
                make_int2(pk2(fmaxf(acc[0], 0.f), fmaxf(acc[1], 0.f)),
                          pk2(fmaxf(acc[2], 0.f), fmaxf(acc[3], 0.f)));
        }
        WG_BARRIER();
        short8 bh0 = *(short8*)&hbuf[c * 136 + q * 8];
        short8 bh1 = *(short8*)&hbuf[c * 136 + 32 + q * 8];
        short8 bh2 = *(short8*)&hbuf[c * 136 + 64 + q * 8];
        short8 bh3 = *(short8*)&hbuf[c * 136 + 96 + q * 8];

        // ---- MFMA2: Z' rows [16w,16w+16), two depth-2 chains + add ----
        f32x4 acc_a = __builtin_amdgcn_mfma_f32_16x16x32_bf16(aw1[0], bh0, cin, 0, 0, 0);
        acc_a = __builtin_amdgcn_mfma_f32_16x16x32_bf16(aw1[1], bh1, acc_a, 0, 0, 0);
        f32x4 acc_b = __builtin_amdgcn_mfma_f32_16x16x32_bf16(aw1[2], bh2, zero4, 0, 0, 0);
        acc_b = __builtin_amdgcn_mfma_f32_16x16x32_bf16(aw1[3], bh3, acc_b, 0, 0, 0);

        #pragma unroll
        for (int e = 0; e < 4; ++e)
            zf[e] = __builtin_amdgcn_fmed3f(acc_a[e] + acc_b[e], -5.f, 5.f);

        // next cin = A*z' + u(T+1)
        cin[0] = fmaf(zf[0], af[0], __int_as_float(tail.x << 16));
        cin[1] = fmaf(zf[1], af[1], __int_as_float(tail.x & 0xffff0000));
        cin[2] = fmaf(zf[2], af[2], __int_as_float(tail.y << 16));
        cin[3] = fmaf(zf[3], af[3], __int_as_float(tail.y & 0xffff0000));
    };

    for (int t = 0; t < TSTEPS; t += 2) {
        step(uP, uQ, t);       // even: prefetch->uP, tail uses uQ = u(t+1)
        step(uQ, uP, t + 1);   // odd:  prefetch->uQ, tail uses uP = u(t+2)
    }

    // ---- epilogue: out = Wout @ Z + bout (waves 0,1) ----
    *(int2*)&zbuf[c * 72 + w * 16 + q * 4] =
        make_int2(pk2(zf[0], zf[1]), pk2(zf[2], zf[3]));
    WG_BARRIER();
    if (w < 2) {
        short8 fz0 = *(short8*)&zbuf[c * 72 + q * 8];
        short8 fz1 = *(short8*)&zbuf[c * 72 + 32 + q * 8];
        const float* p0 = Wout + (w * 16 + c) * NL + q * 8;
        const float* p1 = p0 + 32;
        short8 fa, fb;
        #pragma unroll
        for (int j = 0; j < 8; ++j) { fa[j] = bf1(p0[j]); fb[j] = bf1(p1[j]); }
        f32x4 cb = *(const f32x4*)(bout + w * 16 + q * 4);
        f32x4 acc = __builtin_amdgcn_mfma_f32_16x16x32_bf16(fa, fz0, cb, 0, 0, 0);
        acc = __builtin_amdgcn_mfma_f32_16x16x32_bf16(fb, fz1, acc, 0, 0, 0);
        *(f32x4*)&out[(bbase + c) * 32 + w * 16 + q * 4] = acc;
    }
}

extern "C" void kernel_launch(void* const* d_in, const int* in_sizes, int n_in,
                              void* d_out, int out_size, void* d_ws, size_t ws_size,
                              hipStream_t stream) {
    const float* input = (const float*)d_in[0];
    const float* A     = (const float*)d_in[1];
    const float* W1    = (const float*)d_in[2];
    const float* W2    = (const float*)d_in[3];
    const float* h1    = (const float*)d_in[4];
    const float* h2    = (const float*)d_in[5];
    const float* C     = (const float*)d_in[6];
    const float* Wout  = (const float*)d_in[7];
    const float* bout  = (const float*)d_in[8];
    float* out = (float*)d_out;

    unsigned short* u16 = (unsigned short*)d_ws;   // 256*1024*64 bf16 = 33.5 MB

    ugemm_mfma<<<dim3(512), dim3(256), 0, stream>>>(input, C, h1, u16);
    plrnn_scan_mfma<<<dim3(16), dim3(256), 0, stream>>>(
        A, W1, W2, h2, u16, Wout, bout, out);
}